// Round 1
// baseline (1299.494 us; speedup 1.0000x reference)
//
#include <hip/hip_runtime.h>
#include <hip/hip_bf16.h>
#include <hip/hip_fp16.h>

// Pipeline:
//  x (4,64,130,130) --conv3x3 valid + bias + maxpool2x2--> p1 (4,64,64,64)
//  p1 --1x1 conv (64->32)--> t2 (4,32,64,64)
//  t2 --3x3 conv pad=1 (32->32)--> t3 (4,32,64,64)
//  [FUSED] 1x1 conv (32->1152) offsets computed IN-REGISTER inside k_deform
//  deform_conv(x, upsample2x(offsets), wd) -> out (4,64,128,128)
//
//  k_deform v3 (fused offsets):
//   - Each thread serves a fixed pooled-pixel column tq = tid&15, so its
//     t3 input column (32 floats) is preloaded to registers ONCE.
//   - Per sub-phase (16 channels), per task (it=0..8): two 32-deep fp32
//     dots vs w3 rows (L2-resident, float4 loads) produce (off_y, off_x)
//     in fp32 (better than the old fp16 t4h round-trip). Kills the 37.7MB
//     t4h HBM write+read and the cold-load stall at each sub-phase head.
//   - Gather fast path: wave-uniform __all(in-bounds) -> 2 aligned float2
//     loads per row (even base x0&~1 keeps 8B alignment; WX=130 even),
//     parity-select the 3 taps. 6 load instrs/task instead of 9 clamped.
//   - Phase-2 MFMA (16x16x32 bf16, XOR-swizzled A tile) + LDS-staged
//     coalesced epilogue unchanged.

#define HX 130
#define WX 130

typedef short bf16x8 __attribute__((ext_vector_type(8)));
typedef float f32x4 __attribute__((ext_vector_type(4)));

static __device__ __forceinline__ unsigned short f2bf(float f) {
    unsigned u = __float_as_uint(f);
    unsigned r = u + 0x7fff + ((u >> 16) & 1);   // round-to-nearest-even
    return (unsigned short)(r >> 16);
}

// A-tile address (in shorts): row pitch 320, 16B-block swizzle
static __device__ __forceinline__ int aoff(int row, int col) {
    return row * 320 + ((((col >> 3) ^ (row & 7))) << 3) + (col & 7);
}

// ---------------- K0: wd (o,c,3,3) -> bf16 wdtb[h(2)][oc(64)][col(288)]
// col = sl*144 + lc*72 + ch*9 + kk for c = h*32 + sl*16 + lc*8 + ch
__global__ __launch_bounds__(256) void k_wdt(const float* __restrict__ wd,
                                             unsigned short* __restrict__ wdtb) {
    int idx = blockIdx.x * 256 + threadIdx.x;   // 64*64*9 = 36864
    if (idx >= 36864) return;
    int o = idx / 576;
    int rem = idx - o * 576;
    int c = rem / 9;
    int kk = rem - c * 9;
    int h = c >> 5;
    int c5 = c & 31;
    int col = (c5 >> 4) * 144 + ((c5 >> 3) & 1) * 72 + (c5 & 7) * 9 + kk;
    wdtb[(size_t)(h * 64 + o) * 288 + col] = f2bf(wd[idx]);
}

// ---------------- K1: conv3x3 valid (64->64) + bias + maxpool 2x2 -> p1
// grid 1024 = b(4) * cog(16, 4 oc) * tile(16, 4 pooled rows); block 256
__global__ __launch_bounds__(256, 4) void k_conv0_pool(const float* __restrict__ x,
                                                       const float* __restrict__ w0,
                                                       const float* __restrict__ b0,
                                                       float* __restrict__ p1) {
    int idx = blockIdx.x;
    int tile = idx & 15;          // 4 pooled rows each
    int cog = (idx >> 4) & 15;    // blockIdx-derived -> weight loads scalar
    int b = idx >> 8;
    int tid = threadIdx.x;
    int pw = tid & 63;
    int phl = tid >> 6;           // 0..3
    int ph = tile * 4 + phl;
    __shared__ float slab[2][10 * WX];        // 2 ci x 1300 floats
    const float* xb = x + (size_t)(b * 64) * HX * WX;
    int row0 = tile * 8;          // x rows row0..row0+9
    const float* xbase = xb + row0 * WX;
    float acc[4][4];
    #pragma unroll
    for (int i = 0; i < 4; ++i)
        #pragma unroll
        for (int j = 0; j < 4; ++j) acc[i][j] = 0.f;

    float pre[11];
    #pragma unroll
    for (int j = 0; j < 11; ++j) {
        int i = tid + j * 256;    // 0..2599 covers both ci slabs
        int ci = i / 1300, off = i - ci * 1300;
        pre[j] = (i < 2600) ? xbase[(size_t)ci * (HX * WX) + off] : 0.f;
    }

    for (int cg = 0; cg < 32; ++cg) {         // 2 ci per stage
        __syncthreads();
        #pragma unroll
        for (int j = 0; j < 11; ++j) {
            int i = tid + j * 256;
            if (i < 2600) ((float*)slab)[i] = pre[j];
        }
        __syncthreads();
        if (cg < 31) {
            const float* xp = xbase + (size_t)(2 * cg + 2) * (HX * WX);
            #pragma unroll
            for (int j = 0; j < 11; ++j) {
                int i = tid + j * 256;
                int ci = i / 1300, off = i - ci * 1300;
                pre[j] = (i < 2600) ? xp[(size_t)ci * (HX * WX) + off] : 0.f;
            }
        }
        #pragma unroll
        for (int lc = 0; lc < 2; ++lc) {
            int ci = 2 * cg + lc;
            float v[4][4];
            #pragma unroll
            for (int r2 = 0; r2 < 4; ++r2) {
                const float* rp = &slab[lc][(2 * phl + r2) * WX + 2 * pw];
                float2 a = *(const float2*)rp;
                float2 bb = *(const float2*)(rp + 2);
                v[r2][0] = a.x; v[r2][1] = a.y; v[r2][2] = bb.x; v[r2][3] = bb.y;
            }
            #pragma unroll
            for (int i = 0; i < 4; ++i) {
                const float* wp = w0 + (((cog * 4 + i) * 64) + ci) * 9;  // uniform
                float w[9];
                #pragma unroll
                for (int k = 0; k < 9; ++k) w[k] = wp[k];
                #pragma unroll
                for (int dr = 0; dr < 2; ++dr)
                    #pragma unroll
                    for (int dc = 0; dc < 2; ++dc) {
                        float s = acc[i][dr * 2 + dc];
                        #pragma unroll
                        for (int ky = 0; ky < 3; ++ky)
                            #pragma unroll
                            for (int kx = 0; kx < 3; ++kx)
                                s += w[ky * 3 + kx] * v[dr + ky][dc + kx];
                        acc[i][dr * 2 + dc] = s;
                    }
            }
        }
    }
    #pragma unroll
    for (int i = 0; i < 4; ++i) {
        float m = fmaxf(fmaxf(acc[i][0], acc[i][1]), fmaxf(acc[i][2], acc[i][3]))
                + b0[cog * 4 + i];
        p1[(((size_t)b * 64 + cog * 4 + i) * 64 + ph) * 64 + pw] = m;
    }
}

// ---------------- K2: 1x1 conv 64->32 on 64x64; grid 1024 (2 oc/thread)
__global__ __launch_bounds__(256) void k_conv1x1_a(const float* __restrict__ p1,
                                                   const float* __restrict__ w1,
                                                   const float* __restrict__ b1,
                                                   float* __restrict__ t2) {
    int blk = blockIdx.x;
    int pt = blk & 15;
    int cog = (blk >> 4) & 15;
    int b = blk >> 8;
    int p = pt * 256 + threadIdx.x;
    float acc[2];
    #pragma unroll
    for (int i = 0; i < 2; ++i) acc[i] = b1[cog * 2 + i];
    const float* ip = p1 + (size_t)b * 64 * 4096 + p;
    for (int ci = 0; ci < 64; ++ci) {
        float v = ip[(size_t)ci * 4096];
        #pragma unroll
        for (int i = 0; i < 2; ++i) acc[i] += w1[(cog * 2 + i) * 64 + ci] * v;
    }
    float* op = t2 + (size_t)b * 32 * 4096 + p;
    #pragma unroll
    for (int i = 0; i < 2; ++i) op[(size_t)(cog * 2 + i) * 4096] = acc[i];
}

// ---------------- K3: 3x3 conv pad=1, 32->32 on 64x64; grid 1024 (2 oc/thread)
__global__ __launch_bounds__(256) void k_conv3x3_b(const float* __restrict__ t2,
                                                   const float* __restrict__ w2,
                                                   const float* __restrict__ b2,
                                                   float* __restrict__ t3) {
    int blk = blockIdx.x;
    int pt = blk & 15;
    int cog = (blk >> 4) & 15;
    int b = blk >> 8;
    int p = pt * 256 + threadIdx.x;
    int hy = p >> 6, wx = p & 63;
    float acc[2];
    #pragma unroll
    for (int i = 0; i < 2; ++i) acc[i] = b2[cog * 2 + i];
    const float* ip = t2 + (size_t)b * 32 * 4096;
    for (int ci = 0; ci < 32; ++ci) {
        float v[9];
        #pragma unroll
        for (int ky = 0; ky < 3; ++ky) {
            int yy = hy + ky - 1;
            #pragma unroll
            for (int kx = 0; kx < 3; ++kx) {
                int xx = wx + kx - 1;
                bool ok = (yy >= 0 && yy < 64 && xx >= 0 && xx < 64);
                int yc = min(max(yy, 0), 63), xc = min(max(xx, 0), 63);
                float val = ip[(size_t)ci * 4096 + yc * 64 + xc];
                v[ky * 3 + kx] = ok ? val : 0.f;
            }
        }
        #pragma unroll
        for (int i = 0; i < 2; ++i) {
            const float* wp = w2 + (((cog * 2 + i) * 32) + ci) * 9;   // uniform
            float s = acc[i];
            #pragma unroll
            for (int k = 0; k < 9; ++k) s += wp[k] * v[k];
            acc[i] = s;
        }
    }
    float* op = t3 + (size_t)b * 32 * 4096 + p;
    #pragma unroll
    for (int i = 0; i < 2; ++i) op[(size_t)(cog * 2 + i) * 4096] = acc[i];
}

// ---------------- K5: deformable conv, fused offset conv + MFMA (v3)
// grid 1024 = strip(256)*4 + b. block 256 = 4 waves; wave w owns px rows
// w*16..w*16+15. Per half h: 2 phase-1 sub-phases (16 ch each). Each task
// (it,tid) -> (tq = tid&15 fixed per thread, kcol = it*16 + (tid>>4)):
//   offsets = two fp32 32-dots (w3 rows x resident t3 column), then
//   bilinear gather (fast path: 2 aligned float2 per row) -> 4 bf16 A-rows.
__global__ __launch_bounds__(256, 4) void k_deform(const float* __restrict__ x,
                                                   const float* __restrict__ t3,
                                                   const float* __restrict__ w3,
                                                   const float* __restrict__ b3,
                                                   const unsigned short* __restrict__ wdtb,
                                                   float* __restrict__ out) {
    int blk = blockIdx.x;
    int b = blk & 3;
    int strip = blk >> 2;         // 0..255
    int tid = threadIdx.x;
    int po0 = strip * 16;
    int qy = po0 >> 6;            // strip lies in one quad-row
    int qx0 = po0 & 63;
    int w = tid >> 6;             // wave id
    int lane = tid & 63;
    int lm = lane & 15;
    int lq = lane >> 4;
    int tq = tid & 15;            // pooled-px column this thread serves (fixed)
    int kb = tid >> 4;            // kcol = it*16 + kb

    __shared__ __align__(16) unsigned short alds[64 * 320];   // 40960 B

    f32x4 acc[4];
    #pragma unroll
    for (int n = 0; n < 4; ++n) acc[n] = (f32x4){0.f, 0.f, 0.f, 0.f};

    const float* xb = x + (size_t)b * 64 * HX * WX;

    // preload this thread's t3 column (32 ci) into registers
    float v3[32];
    {
        const float* t3p = t3 + (size_t)b * 32 * 4096 + (qy * 64 + qx0 + tq);
        #pragma unroll
        for (int ci = 0; ci < 32; ++ci) v3[ci] = t3p[(size_t)ci * 4096];
    }

    for (int h = 0; h < 2; ++h) {
        #pragma unroll 1
        for (int sl = 0; sl < 2; ++sl) {
            int s = h * 2 + sl;           // sup = 16 channels
            __syncthreads();              // alds free (prev phase-2 done) + phase-lock

            // ---- phase 1a: offsets via fused 1x1 conv (fp32, in-register)
            float pys[9], pxs[9];
            #pragma unroll
            for (int it = 0; it < 9; ++it) {
                int kcol = it * 16 + kb;      // 0..143
                int lc = kcol >= 72;
                int ckk = kcol - 72 * lc;     // 0..71
                int ch = (ckk * 57) >> 9;     // /9
                int kk = ckk - ch * 9;
                int gp = s * 144 + lc * 72 + ckk;     // channel-pair = c*9 + kk
                int chE = 2 * gp;
                const f32x4* wq = (const f32x4*)(w3 + (size_t)chE * 32);
                float accE = b3[chE], accO = b3[chE + 1];
                #pragma unroll
                for (int q = 0; q < 8; ++q) {
                    f32x4 we = wq[q];
                    f32x4 wo = wq[8 + q];
                    accE += we.x * v3[4*q] + we.y * v3[4*q+1]
                          + we.z * v3[4*q+2] + we.w * v3[4*q+3];
                    accO += wo.x * v3[4*q] + wo.y * v3[4*q+1]
                          + wo.z * v3[4*q+2] + wo.w * v3[4*q+3];
                }
                pys[it] = accE + (float)(2 * qy + kk / 3);
                pxs[it] = accO + (float)(2 * (qx0 + tq) + kk % 3);
            }

            // ---- phase 1b: bilinear gather -> 4 bf16 A-tile rows per task
            #pragma unroll
            for (int it = 0; it < 9; ++it) {
                int kcol = it * 16 + kb;
                int lc = kcol >= 72;
                int ckk = kcol - 72 * lc;
                int ch = (ckk * 57) >> 9;
                int c = s * 16 + lc * 8 + ch;
                int clocal = sl * 144 + kcol; // A column 0..287
                float py = pys[it], px = pxs[it];
                float y0f = floorf(py), x0f = floorf(px);
                float fy = py - y0f, fx = px - x0f;
                int y0 = (int)y0f, x0 = (int)x0f;
                const float* xp = xb + (size_t)c * (HX * WX);
                float tv[3][3];
                bool fastok = (y0 >= 0) & (y0 <= HX - 3) & (x0 >= 0) & (x0 <= WX - 3);
                if (__all(fastok)) {
                    // whole wave in-bounds: even-aligned float2 pair per row
                    int xe = x0 & ~1;         // even -> 8B-aligned (WX even)
                    int odd = x0 & 1;
                    const float* rp = xp + y0 * WX + xe;
                    #pragma unroll
                    for (int r = 0; r < 3; ++r) {
                        float2 A = *(const float2*)(rp);
                        float2 B = *(const float2*)(rp + 2);
                        tv[r][0] = odd ? A.y : A.x;
                        tv[r][1] = odd ? B.x : A.y;
                        tv[r][2] = odd ? B.y : B.x;
                        rp += WX;
                    }
                } else {
                    #pragma unroll
                    for (int r = 0; r < 3; ++r) {
                        int yy = y0 + r;
                        bool vy = (yy >= 0) & (yy < HX);
                        int yc = min(max(yy, 0), HX - 1);
                        #pragma unroll
                        for (int sx = 0; sx < 3; ++sx) {
                            int xx = x0 + sx;
                            bool vx = (xx >= 0) & (xx < WX);
                            int xc = min(max(xx, 0), WX - 1);
                            float val = xp[yc * WX + xc];
                            tv[r][sx] = (vy & vx) ? val : 0.f;
                        }
                    }
                }
                float h0[3], h1[3];
                #pragma unroll
                for (int r = 0; r < 3; ++r) {
                    h0[r] = tv[r][0] + fx * (tv[r][1] - tv[r][0]);
                    h1[r] = tv[r][1] + fx * (tv[r][2] - tv[r][1]);
                }
                alds[aoff(0 * 16 + tq, clocal)] = f2bf(h0[0] + fy * (h0[1] - h0[0]));
                alds[aoff(1 * 16 + tq, clocal)] = f2bf(h1[0] + fy * (h1[1] - h1[0]));
                alds[aoff(2 * 16 + tq, clocal)] = f2bf(h0[1] + fy * (h0[2] - h0[1]));
                alds[aoff(3 * 16 + tq, clocal)] = f2bf(h1[1] + fy * (h1[2] - h1[1]));
            }
        }
        __syncthreads();          // A-tile (288 cols) visible

        // ---- phase 2: D[64px][64oc] += V[64][288] . W^T  (MFMA)
        int arow = w * 16 + lm;
        const unsigned short* bbase = wdtb + (size_t)(h * 64) * 288;
        #pragma unroll
        for (int ks = 0; ks < 9; ++ks) {
            bf16x8 a = *(const bf16x8*)&alds[aoff(arow, ks * 32 + lq * 8)];
            #pragma unroll
            for (int n = 0; n < 4; ++n) {
                bf16x8 bb = *(const bf16x8*)(bbase + (size_t)(n * 16 + lm) * 288
                                             + ks * 32 + lq * 8);
                acc[n] = __builtin_amdgcn_mfma_f32_16x16x32_bf16(a, bb, acc[n], 0, 0, 0);
            }
        }
    }

    // ---- epilogue via LDS: D lane layout -> [oc][px] -> coalesced stores
    __syncthreads();              // all phase-2 reads of alds complete
    float* dlds = (float*)alds;   // 64*65 = 4160 floats (16.6 KB of 40.9)
    #pragma unroll
    for (int n = 0; n < 4; ++n) {
        int oc = n * 16 + lm;
        #pragma unroll
        for (int r = 0; r < 4; ++r) {
            int px = w * 16 + lq * 4 + r;     // = sub*16 + q
            dlds[oc * 65 + px] = acc[n][r];
        }
    }
    __syncthreads();
    {
        int oc = tid >> 2;
        int sy = (tid >> 1) & 1;
        int qh = (tid & 1) * 8;
        float* orow = out + (((size_t)b * 64 + oc) * 128 + 2 * qy + sy) * 128 + 2 * qx0;
        const float* d0 = &dlds[oc * 65 + (sy * 2 + 0) * 16];
        const float* d1 = &dlds[oc * 65 + (sy * 2 + 1) * 16];
        #pragma unroll
        for (int i = 0; i < 8; ++i) {
            int q = qh + i;
            *(float2*)(orow + 2 * q) = make_float2(d0[q], d1[q]);
        }
    }
}

extern "C" void kernel_launch(void* const* d_in, const int* in_sizes, int n_in,
                              void* d_out, int out_size, void* d_ws, size_t ws_size,
                              hipStream_t stream) {
    const float* x  = (const float*)d_in[0];
    const float* w0 = (const float*)d_in[1];
    const float* b0 = (const float*)d_in[2];
    const float* w1 = (const float*)d_in[3];
    const float* b1 = (const float*)d_in[4];
    const float* w2 = (const float*)d_in[5];
    const float* b2 = (const float*)d_in[6];
    const float* w3 = (const float*)d_in[7];
    const float* b3 = (const float*)d_in[8];
    const float* wd = (const float*)d_in[9];
    float* out = (float*)d_out;

    float* ws = (float*)d_ws;
    float* p1    = ws;                       // 1,048,576 floats
    float* t2    = p1 + 1048576;             //   524,288
    float* t3    = t2 + 524288;              //   524,288
    unsigned short* wdtb = (unsigned short*)(t3 + 524288);  // 36,864 bf16

    k_wdt<<<144, 256, 0, stream>>>(wd, wdtb);
    k_conv0_pool<<<1024, 256, 0, stream>>>(x, w0, b0, p1);
    k_conv1x1_a<<<1024, 256, 0, stream>>>(p1, w1, b1, t2);
    k_conv3x3_b<<<1024, 256, 0, stream>>>(t2, w2, b2, t3);
    k_deform<<<1024, 256, 0, stream>>>(x, t3, w3, b3, wdtb, out);
}

// Round 2
// 512.752 us; speedup vs baseline: 2.5344x; 2.5344x over previous
//
#include <hip/hip_runtime.h>
#include <hip/hip_bf16.h>
#include <hip/hip_fp16.h>

// Pipeline:
//  x (4,64,130,130) --conv3x3 valid + bias + maxpool2x2--> p1 (4,64,64,64)
//  p1 --1x1 conv (64->32)--> t2 (4,32,64,64)
//  t2 --3x3 conv pad=1 (32->32)--> t3 (4,32,64,64)
//  [FUSED] 1x1 conv (32->1152) offsets computed in k_deform (fp32)
//  deform_conv(x, upsample2x(offsets), wd) -> out (4,64,128,128)
//
//  k_deform v4 (fused offsets, spill-safe):
//   - v3's failure: two fully-unrolled x9 loops + v3[32]/pys[9]/pxs[9] live
//     -> compiler interleaved 9 dot chains + 144 in-flight loads -> scratch
//     spills (WRITE_SIZE 1.9 GB). v4 bounds pressure:
//   - Group-of-3 pipeline, `#pragma unroll 1` on the group loop: per group,
//     3 offset dots (t3 read from global: 16-consecutive-float wave segment,
//     L1-resident; w3 f32x4 from L2) -> named py[u]/px[u] (static idx) ->
//     3 bilinear gathers (wave-uniform fast path, aligned float2 pairs).
//   - No per-thread t3 residency, no 9-wide arrays. ~90 VGPR live max.
//   - Phase-2 MFMA (16x16x32 bf16, XOR-swizzled A tile) + LDS-staged
//     coalesced epilogue unchanged.

#define HX 130
#define WX 130

typedef short bf16x8 __attribute__((ext_vector_type(8)));
typedef float f32x4 __attribute__((ext_vector_type(4)));

static __device__ __forceinline__ unsigned short f2bf(float f) {
    unsigned u = __float_as_uint(f);
    unsigned r = u + 0x7fff + ((u >> 16) & 1);   // round-to-nearest-even
    return (unsigned short)(r >> 16);
}

// A-tile address (in shorts): row pitch 320, 16B-block swizzle
static __device__ __forceinline__ int aoff(int row, int col) {
    return row * 320 + ((((col >> 3) ^ (row & 7))) << 3) + (col & 7);
}

// ---------------- K0: wd (o,c,3,3) -> bf16 wdtb[h(2)][oc(64)][col(288)]
// col = sl*144 + lc*72 + ch*9 + kk for c = h*32 + sl*16 + lc*8 + ch
__global__ __launch_bounds__(256) void k_wdt(const float* __restrict__ wd,
                                             unsigned short* __restrict__ wdtb) {
    int idx = blockIdx.x * 256 + threadIdx.x;   // 64*64*9 = 36864
    if (idx >= 36864) return;
    int o = idx / 576;
    int rem = idx - o * 576;
    int c = rem / 9;
    int kk = rem - c * 9;
    int h = c >> 5;
    int c5 = c & 31;
    int col = (c5 >> 4) * 144 + ((c5 >> 3) & 1) * 72 + (c5 & 7) * 9 + kk;
    wdtb[(size_t)(h * 64 + o) * 288 + col] = f2bf(wd[idx]);
}

// ---------------- K1: conv3x3 valid (64->64) + bias + maxpool 2x2 -> p1
// grid 1024 = b(4) * cog(16, 4 oc) * tile(16, 4 pooled rows); block 256
__global__ __launch_bounds__(256, 4) void k_conv0_pool(const float* __restrict__ x,
                                                       const float* __restrict__ w0,
                                                       const float* __restrict__ b0,
                                                       float* __restrict__ p1) {
    int idx = blockIdx.x;
    int tile = idx & 15;          // 4 pooled rows each
    int cog = (idx >> 4) & 15;    // blockIdx-derived -> weight loads scalar
    int b = idx >> 8;
    int tid = threadIdx.x;
    int pw = tid & 63;
    int phl = tid >> 6;           // 0..3
    int ph = tile * 4 + phl;
    __shared__ float slab[2][10 * WX];        // 2 ci x 1300 floats
    const float* xb = x + (size_t)(b * 64) * HX * WX;
    int row0 = tile * 8;          // x rows row0..row0+9
    const float* xbase = xb + row0 * WX;
    float acc[4][4];
    #pragma unroll
    for (int i = 0; i < 4; ++i)
        #pragma unroll
        for (int j = 0; j < 4; ++j) acc[i][j] = 0.f;

    float pre[11];
    #pragma unroll
    for (int j = 0; j < 11; ++j) {
        int i = tid + j * 256;    // 0..2599 covers both ci slabs
        int ci = i / 1300, off = i - ci * 1300;
        pre[j] = (i < 2600) ? xbase[(size_t)ci * (HX * WX) + off] : 0.f;
    }

    for (int cg = 0; cg < 32; ++cg) {         // 2 ci per stage
        __syncthreads();
        #pragma unroll
        for (int j = 0; j < 11; ++j) {
            int i = tid + j * 256;
            if (i < 2600) ((float*)slab)[i] = pre[j];
        }
        __syncthreads();
        if (cg < 31) {
            const float* xp = xbase + (size_t)(2 * cg + 2) * (HX * WX);
            #pragma unroll
            for (int j = 0; j < 11; ++j) {
                int i = tid + j * 256;
                int ci = i / 1300, off = i - ci * 1300;
                pre[j] = (i < 2600) ? xp[(size_t)ci * (HX * WX) + off] : 0.f;
            }
        }
        #pragma unroll
        for (int lc = 0; lc < 2; ++lc) {
            int ci = 2 * cg + lc;
            float v[4][4];
            #pragma unroll
            for (int r2 = 0; r2 < 4; ++r2) {
                const float* rp = &slab[lc][(2 * phl + r2) * WX + 2 * pw];
                float2 a = *(const float2*)rp;
                float2 bb = *(const float2*)(rp + 2);
                v[r2][0] = a.x; v[r2][1] = a.y; v[r2][2] = bb.x; v[r2][3] = bb.y;
            }
            #pragma unroll
            for (int i = 0; i < 4; ++i) {
                const float* wp = w0 + (((cog * 4 + i) * 64) + ci) * 9;  // uniform
                float w[9];
                #pragma unroll
                for (int k = 0; k < 9; ++k) w[k] = wp[k];
                #pragma unroll
                for (int dr = 0; dr < 2; ++dr)
                    #pragma unroll
                    for (int dc = 0; dc < 2; ++dc) {
                        float s = acc[i][dr * 2 + dc];
                        #pragma unroll
                        for (int ky = 0; ky < 3; ++ky)
                            #pragma unroll
                            for (int kx = 0; kx < 3; ++kx)
                                s += w[ky * 3 + kx] * v[dr + ky][dc + kx];
                        acc[i][dr * 2 + dc] = s;
                    }
            }
        }
    }
    #pragma unroll
    for (int i = 0; i < 4; ++i) {
        float m = fmaxf(fmaxf(acc[i][0], acc[i][1]), fmaxf(acc[i][2], acc[i][3]))
                + b0[cog * 4 + i];
        p1[(((size_t)b * 64 + cog * 4 + i) * 64 + ph) * 64 + pw] = m;
    }
}

// ---------------- K2: 1x1 conv 64->32 on 64x64; grid 1024 (2 oc/thread)
__global__ __launch_bounds__(256) void k_conv1x1_a(const float* __restrict__ p1,
                                                   const float* __restrict__ w1,
                                                   const float* __restrict__ b1,
                                                   float* __restrict__ t2) {
    int blk = blockIdx.x;
    int pt = blk & 15;
    int cog = (blk >> 4) & 15;
    int b = blk >> 8;
    int p = pt * 256 + threadIdx.x;
    float acc[2];
    #pragma unroll
    for (int i = 0; i < 2; ++i) acc[i] = b1[cog * 2 + i];
    const float* ip = p1 + (size_t)b * 64 * 4096 + p;
    for (int ci = 0; ci < 64; ++ci) {
        float v = ip[(size_t)ci * 4096];
        #pragma unroll
        for (int i = 0; i < 2; ++i) acc[i] += w1[(cog * 2 + i) * 64 + ci] * v;
    }
    float* op = t2 + (size_t)b * 32 * 4096 + p;
    #pragma unroll
    for (int i = 0; i < 2; ++i) op[(size_t)(cog * 2 + i) * 4096] = acc[i];
}

// ---------------- K3: 3x3 conv pad=1, 32->32 on 64x64; grid 1024 (2 oc/thread)
__global__ __launch_bounds__(256) void k_conv3x3_b(const float* __restrict__ t2,
                                                   const float* __restrict__ w2,
                                                   const float* __restrict__ b2,
                                                   float* __restrict__ t3) {
    int blk = blockIdx.x;
    int pt = blk & 15;
    int cog = (blk >> 4) & 15;
    int b = blk >> 8;
    int p = pt * 256 + threadIdx.x;
    int hy = p >> 6, wx = p & 63;
    float acc[2];
    #pragma unroll
    for (int i = 0; i < 2; ++i) acc[i] = b2[cog * 2 + i];
    const float* ip = t2 + (size_t)b * 32 * 4096;
    for (int ci = 0; ci < 32; ++ci) {
        float v[9];
        #pragma unroll
        for (int ky = 0; ky < 3; ++ky) {
            int yy = hy + ky - 1;
            #pragma unroll
            for (int kx = 0; kx < 3; ++kx) {
                int xx = wx + kx - 1;
                bool ok = (yy >= 0 && yy < 64 && xx >= 0 && xx < 64);
                int yc = min(max(yy, 0), 63), xc = min(max(xx, 0), 63);
                float val = ip[(size_t)ci * 4096 + yc * 64 + xc];
                v[ky * 3 + kx] = ok ? val : 0.f;
            }
        }
        #pragma unroll
        for (int i = 0; i < 2; ++i) {
            const float* wp = w2 + (((cog * 2 + i) * 32) + ci) * 9;   // uniform
            float s = acc[i];
            #pragma unroll
            for (int k = 0; k < 9; ++k) s += wp[k] * v[k];
            acc[i] = s;
        }
    }
    float* op = t3 + (size_t)b * 32 * 4096 + p;
    #pragma unroll
    for (int i = 0; i < 2; ++i) op[(size_t)(cog * 2 + i) * 4096] = acc[i];
}

// ---------------- K5: deformable conv, fused offset conv + MFMA (v4)
// grid 1024 = strip(256)*4 + b. block 256 = 4 waves; wave w owns px rows
// w*16..w*16+15. Per half h: 2 phase-1 sub-phases (16 ch each). Task
// (it,tid): tq = tid&15 (pooled px), kcol = it*16 + (tid>>4).
// Tasks processed in 3 groups of 3: {3 offset dots} then {3 gathers}.
__global__ __launch_bounds__(256, 4) void k_deform(const float* __restrict__ x,
                                                   const float* __restrict__ t3,
                                                   const float* __restrict__ w3,
                                                   const float* __restrict__ b3,
                                                   const unsigned short* __restrict__ wdtb,
                                                   float* __restrict__ out) {
    int blk = blockIdx.x;
    int b = blk & 3;
    int strip = blk >> 2;         // 0..255
    int tid = threadIdx.x;
    int po0 = strip * 16;
    int qy = po0 >> 6;            // strip lies in one quad-row
    int qx0 = po0 & 63;
    int w = tid >> 6;             // wave id
    int lane = tid & 63;
    int lm = lane & 15;
    int lq = lane >> 4;
    int tq = tid & 15;            // pooled-px column this thread serves (fixed)
    int kb = tid >> 4;            // kcol = it*16 + kb

    __shared__ __align__(16) unsigned short alds[64 * 320];   // 40960 B

    f32x4 acc[4];
    #pragma unroll
    for (int n = 0; n < 4; ++n) acc[n] = (f32x4){0.f, 0.f, 0.f, 0.f};

    const float* xb = x + (size_t)b * 64 * HX * WX;
    // this thread's t3 column base: 16-consecutive-float wave segment,
    // L1-resident after first touch (block working set ~4 KB)
    const float* t3c = t3 + (size_t)b * 32 * 4096 + (qy * 64 + qx0 + tq);
    float fybase = (float)(2 * qy);
    float fxbase = (float)(2 * (qx0 + tq));

    for (int h = 0; h < 2; ++h) {
        #pragma unroll 1
        for (int sl = 0; sl < 2; ++sl) {
            int s = h * 2 + sl;           // sup = 16 channels
            __syncthreads();              // alds free (prev phase-2 done) + phase-lock

            #pragma unroll 1
            for (int g = 0; g < 3; ++g) {     // 3 tasks per group
                float py[3], px[3];
                int cch[3], ccl[3];
                // ---- dots: offsets via fused 1x1 conv (fp32)
                #pragma unroll
                for (int u = 0; u < 3; ++u) {
                    int it = g * 3 + u;
                    int kcol = it * 16 + kb;      // 0..143
                    int lc = kcol >= 72;
                    int ckk = kcol - 72 * lc;     // 0..71
                    int ch = (ckk * 57) >> 9;     // /9
                    int kk = ckk - ch * 9;
                    cch[u] = s * 16 + lc * 8 + ch;        // x channel
                    ccl[u] = sl * 144 + kcol;             // A column 0..287
                    int chE = 2 * (s * 144 + lc * 72 + ckk);  // = c*18 + 2*kk
                    const f32x4* wq = (const f32x4*)(w3 + (size_t)chE * 32);
                    float2 bias = *(const float2*)(b3 + chE);
                    float accE = bias.x, accO = bias.y;
                    #pragma unroll
                    for (int q = 0; q < 8; ++q) {
                        f32x4 we = wq[q];
                        f32x4 wo = wq[8 + q];
                        float v0 = t3c[(size_t)(4 * q + 0) * 4096];
                        float v1 = t3c[(size_t)(4 * q + 1) * 4096];
                        float v2 = t3c[(size_t)(4 * q + 2) * 4096];
                        float v3v = t3c[(size_t)(4 * q + 3) * 4096];
                        accE += we.x * v0 + we.y * v1 + we.z * v2 + we.w * v3v;
                        accO += wo.x * v0 + wo.y * v1 + wo.z * v2 + wo.w * v3v;
                    }
                    py[u] = accE + fybase + (float)(kk / 3);
                    px[u] = accO + fxbase + (float)(kk % 3);
                }
                // ---- gathers: bilinear -> 4 bf16 A-tile rows per task
                #pragma unroll
                for (int u = 0; u < 3; ++u) {
                    int c = cch[u];
                    int clocal = ccl[u];
                    float pyv = py[u], pxv = px[u];
                    float y0f = floorf(pyv), x0f = floorf(pxv);
                    float fy = pyv - y0f, fx = pxv - x0f;
                    int y0 = (int)y0f, x0 = (int)x0f;
                    const float* xp = xb + (size_t)c * (HX * WX);
                    float tv[3][3];
                    bool fastok = (y0 >= 0) & (y0 <= HX - 3) & (x0 >= 0) & (x0 <= WX - 3);
                    if (__all(fastok)) {
                        // whole wave in-bounds: even-aligned float2 pair per row
                        int xe = x0 & ~1;         // even -> 8B-aligned (WX even)
                        int odd = x0 & 1;
                        const float* rp = xp + y0 * WX + xe;
                        #pragma unroll
                        for (int r = 0; r < 3; ++r) {
                            float2 A = *(const float2*)(rp);
                            float2 B = *(const float2*)(rp + 2);
                            tv[r][0] = odd ? A.y : A.x;
                            tv[r][1] = odd ? B.x : A.y;
                            tv[r][2] = odd ? B.y : B.x;
                            rp += WX;
                        }
                    } else {
                        #pragma unroll
                        for (int r = 0; r < 3; ++r) {
                            int yy = y0 + r;
                            bool vy = (yy >= 0) & (yy < HX);
                            int yc = min(max(yy, 0), HX - 1);
                            #pragma unroll
                            for (int sx = 0; sx < 3; ++sx) {
                                int xx = x0 + sx;
                                bool vx = (xx >= 0) & (xx < WX);
                                int xc = min(max(xx, 0), WX - 1);
                                float val = xp[yc * WX + xc];
                                tv[r][sx] = (vy & vx) ? val : 0.f;
                            }
                        }
                    }
                    float h0[3], h1[3];
                    #pragma unroll
                    for (int r = 0; r < 3; ++r) {
                        h0[r] = tv[r][0] + fx * (tv[r][1] - tv[r][0]);
                        h1[r] = tv[r][1] + fx * (tv[r][2] - tv[r][1]);
                    }
                    alds[aoff(0 * 16 + tq, clocal)] = f2bf(h0[0] + fy * (h0[1] - h0[0]));
                    alds[aoff(1 * 16 + tq, clocal)] = f2bf(h1[0] + fy * (h1[1] - h1[0]));
                    alds[aoff(2 * 16 + tq, clocal)] = f2bf(h0[1] + fy * (h0[2] - h0[1]));
                    alds[aoff(3 * 16 + tq, clocal)] = f2bf(h1[1] + fy * (h1[2] - h1[1]));
                }
            }
        }
        __syncthreads();          // A-tile (288 cols) visible

        // ---- phase 2: D[64px][64oc] += V[64][288] . W^T  (MFMA)
        int arow = w * 16 + lm;
        const unsigned short* bbase = wdtb + (size_t)(h * 64) * 288;
        #pragma unroll
        for (int ks = 0; ks < 9; ++ks) {
            bf16x8 a = *(const bf16x8*)&alds[aoff(arow, ks * 32 + lq * 8)];
            #pragma unroll
            for (int n = 0; n < 4; ++n) {
                bf16x8 bb = *(const bf16x8*)(bbase + (size_t)(n * 16 + lm) * 288
                                             + ks * 32 + lq * 8);
                acc[n] = __builtin_amdgcn_mfma_f32_16x16x32_bf16(a, bb, acc[n], 0, 0, 0);
            }
        }
    }

    // ---- epilogue via LDS: D lane layout -> [oc][px] -> coalesced stores
    __syncthreads();              // all phase-2 reads of alds complete
    float* dlds = (float*)alds;   // 64*65 = 4160 floats (16.6 KB of 40.9)
    #pragma unroll
    for (int n = 0; n < 4; ++n) {
        int oc = n * 16 + lm;
        #pragma unroll
        for (int r = 0; r < 4; ++r) {
            int px = w * 16 + lq * 4 + r;     // = sub*16 + q
            dlds[oc * 65 + px] = acc[n][r];
        }
    }
    __syncthreads();
    {
        int oc = tid >> 2;
        int sy = (tid >> 1) & 1;
        int qh = (tid & 1) * 8;
        float* orow = out + (((size_t)b * 64 + oc) * 128 + 2 * qy + sy) * 128 + 2 * qx0;
        const float* d0 = &dlds[oc * 65 + (sy * 2 + 0) * 16];
        const float* d1 = &dlds[oc * 65 + (sy * 2 + 1) * 16];
        #pragma unroll
        for (int i = 0; i < 8; ++i) {
            int q = qh + i;
            *(float2*)(orow + 2 * q) = make_float2(d0[q], d1[q]);
        }
    }
}

extern "C" void kernel_launch(void* const* d_in, const int* in_sizes, int n_in,
                              void* d_out, int out_size, void* d_ws, size_t ws_size,
                              hipStream_t stream) {
    const float* x  = (const float*)d_in[0];
    const float* w0 = (const float*)d_in[1];
    const float* b0 = (const float*)d_in[2];
    const float* w1 = (const float*)d_in[3];
    const float* b1 = (const float*)d_in[4];
    const float* w2 = (const float*)d_in[5];
    const float* b2 = (const float*)d_in[6];
    const float* w3 = (const float*)d_in[7];
    const float* b3 = (const float*)d_in[8];
    const float* wd = (const float*)d_in[9];
    float* out = (float*)d_out;

    float* ws = (float*)d_ws;
    float* p1    = ws;                       // 1,048,576 floats
    float* t2    = p1 + 1048576;             //   524,288
    float* t3    = t2 + 524288;              //   524,288
    unsigned short* wdtb = (unsigned short*)(t3 + 524288);  // 36,864 bf16

    k_wdt<<<144, 256, 0, stream>>>(wd, wdtb);
    k_conv0_pool<<<1024, 256, 0, stream>>>(x, w0, b0, p1);
    k_conv1x1_a<<<1024, 256, 0, stream>>>(p1, w1, b1, t2);
    k_conv3x3_b<<<1024, 256, 0, stream>>>(t2, w2, b2, t3);
    k_deform<<<1024, 256, 0, stream>>>(x, t3, w3, b3, wdtb, out);
}

// Round 3
// 250.049 us; speedup vs baseline: 5.1970x; 2.0506x over previous
//
#include <hip/hip_runtime.h>
#include <hip/hip_bf16.h>
#include <hip/hip_fp16.h>

// Pipeline:
//  x (4,64,130,130) --conv3x3 valid + bias + maxpool2x2--> p1 (4,64,64,64)
//  p1 --1x1 conv (64->32)--> t2 (4,32,64,64)
//  t2 --3x3 conv pad=1 (32->32)--> t3 (4,32,64,64)
//  [FUSED] offset conv (32->1152) computed INSIDE k_deform via f16 MFMA
//  deform_conv(x, upsample2x(offsets), wd) -> out (4,64,128,128)
//
//  k_deform v5 (MFMA offsets):
//   - v3/v4 failed: per-thread 32-deep offset dots spill at the 64-VGPR
//     allocation (WRITE_SIZE 1.9GB/542MB of scratch). v5 computes offsets
//     with the matrix pipe instead: per sub-phase,
//       D[288 off-ch][16 px] = w3h[288][32] . t3[32][16]   (K=32, fp16)
//     = 18 mfma_f32_16x16x32_f16 for the whole block (waves share t3 B-frag,
//     read once from LDS). Results (+bias) packed as half2 (py,px) into a
//     9.2 KB LDS buffer soff; phase-1b prefetches o2h[9] per thread from
//     LDS (round-0's proven pattern, minus the t4h HBM round-trip).
//   - t3 tile (32ci x 16px) staged once to LDS as fp16 (pitch 40 halves).
//   - Gather: wave-uniform __all fast path, aligned float2 pairs (v4-proven).
//   - LDS 51.5 KB -> 3 blocks/CU; __launch_bounds__(256,3) lifts VGPR cap.
//   - Phase-2 MFMA (16x16x32 bf16, XOR-swizzled A tile) + LDS-staged
//     coalesced epilogue unchanged (verified since round 0).

#define HX 130
#define WX 130

typedef short bf16x8 __attribute__((ext_vector_type(8)));
typedef _Float16 f16x8 __attribute__((ext_vector_type(8)));
typedef float f32x4 __attribute__((ext_vector_type(4)));

static __device__ __forceinline__ unsigned short f2bf(float f) {
    unsigned u = __float_as_uint(f);
    unsigned r = u + 0x7fff + ((u >> 16) & 1);   // round-to-nearest-even
    return (unsigned short)(r >> 16);
}

// A-tile address (in shorts): row pitch 320, 16B-block swizzle
static __device__ __forceinline__ int aoff(int row, int col) {
    return row * 320 + ((((col >> 3) ^ (row & 7))) << 3) + (col & 7);
}

// ---------------- K0: wd -> bf16 wdtb[h(2)][oc(64)][col(288)]  and
//                     w3 -> fp16 w3h[1152][32]
// grid 288: blocks 0-143 handle wd (36864 elems), 144-287 handle w3 (36864)
__global__ __launch_bounds__(256) void k_wdt(const float* __restrict__ wd,
                                             const float* __restrict__ w3,
                                             unsigned short* __restrict__ wdtb,
                                             __half* __restrict__ w3h) {
    int idx = blockIdx.x * 256 + threadIdx.x;
    if (idx < 36864) {
        int o = idx / 576;
        int rem = idx - o * 576;
        int c = rem / 9;
        int kk = rem - c * 9;
        int h = c >> 5;
        int c5 = c & 31;
        int col = (c5 >> 4) * 144 + ((c5 >> 3) & 1) * 72 + (c5 & 7) * 9 + kk;
        wdtb[(size_t)(h * 64 + o) * 288 + col] = f2bf(wd[idx]);
    } else {
        int i2 = idx - 36864;
        if (i2 < 36864) w3h[i2] = __float2half_rn(w3[i2]);
    }
}

// ---------------- K1: conv3x3 valid (64->64) + bias + maxpool 2x2 -> p1
// grid 1024 = b(4) * cog(16, 4 oc) * tile(16, 4 pooled rows); block 256
__global__ __launch_bounds__(256, 4) void k_conv0_pool(const float* __restrict__ x,
                                                       const float* __restrict__ w0,
                                                       const float* __restrict__ b0,
                                                       float* __restrict__ p1) {
    int idx = blockIdx.x;
    int tile = idx & 15;          // 4 pooled rows each
    int cog = (idx >> 4) & 15;    // blockIdx-derived -> weight loads scalar
    int b = idx >> 8;
    int tid = threadIdx.x;
    int pw = tid & 63;
    int phl = tid >> 6;           // 0..3
    int ph = tile * 4 + phl;
    __shared__ float slab[2][10 * WX];        // 2 ci x 1300 floats
    const float* xb = x + (size_t)(b * 64) * HX * WX;
    int row0 = tile * 8;          // x rows row0..row0+9
    const float* xbase = xb + row0 * WX;
    float acc[4][4];
    #pragma unroll
    for (int i = 0; i < 4; ++i)
        #pragma unroll
        for (int j = 0; j < 4; ++j) acc[i][j] = 0.f;

    float pre[11];
    #pragma unroll
    for (int j = 0; j < 11; ++j) {
        int i = tid + j * 256;    // 0..2599 covers both ci slabs
        int ci = i / 1300, off = i - ci * 1300;
        pre[j] = (i < 2600) ? xbase[(size_t)ci * (HX * WX) + off] : 0.f;
    }

    for (int cg = 0; cg < 32; ++cg) {         // 2 ci per stage
        __syncthreads();
        #pragma unroll
        for (int j = 0; j < 11; ++j) {
            int i = tid + j * 256;
            if (i < 2600) ((float*)slab)[i] = pre[j];
        }
        __syncthreads();
        if (cg < 31) {
            const float* xp = xbase + (size_t)(2 * cg + 2) * (HX * WX);
            #pragma unroll
            for (int j = 0; j < 11; ++j) {
                int i = tid + j * 256;
                int ci = i / 1300, off = i - ci * 1300;
                pre[j] = (i < 2600) ? xp[(size_t)ci * (HX * WX) + off] : 0.f;
            }
        }
        #pragma unroll
        for (int lc = 0; lc < 2; ++lc) {
            int ci = 2 * cg + lc;
            float v[4][4];
            #pragma unroll
            for (int r2 = 0; r2 < 4; ++r2) {
                const float* rp = &slab[lc][(2 * phl + r2) * WX + 2 * pw];
                float2 a = *(const float2*)rp;
                float2 bb = *(const float2*)(rp + 2);
                v[r2][0] = a.x; v[r2][1] = a.y; v[r2][2] = bb.x; v[r2][3] = bb.y;
            }
            #pragma unroll
            for (int i = 0; i < 4; ++i) {
                const float* wp = w0 + (((cog * 4 + i) * 64) + ci) * 9;  // uniform
                float w[9];
                #pragma unroll
                for (int k = 0; k < 9; ++k) w[k] = wp[k];
                #pragma unroll
                for (int dr = 0; dr < 2; ++dr)
                    #pragma unroll
                    for (int dc = 0; dc < 2; ++dc) {
                        float s = acc[i][dr * 2 + dc];
                        #pragma unroll
                        for (int ky = 0; ky < 3; ++ky)
                            #pragma unroll
                            for (int kx = 0; kx < 3; ++kx)
                                s += w[ky * 3 + kx] * v[dr + ky][dc + kx];
                        acc[i][dr * 2 + dc] = s;
                    }
            }
        }
    }
    #pragma unroll
    for (int i = 0; i < 4; ++i) {
        float m = fmaxf(fmaxf(acc[i][0], acc[i][1]), fmaxf(acc[i][2], acc[i][3]))
                + b0[cog * 4 + i];
        p1[(((size_t)b * 64 + cog * 4 + i) * 64 + ph) * 64 + pw] = m;
    }
}

// ---------------- K2: 1x1 conv 64->32 on 64x64; grid 1024 (2 oc/thread)
__global__ __launch_bounds__(256) void k_conv1x1_a(const float* __restrict__ p1,
                                                   const float* __restrict__ w1,
                                                   const float* __restrict__ b1,
                                                   float* __restrict__ t2) {
    int blk = blockIdx.x;
    int pt = blk & 15;
    int cog = (blk >> 4) & 15;
    int b = blk >> 8;
    int p = pt * 256 + threadIdx.x;
    float acc[2];
    #pragma unroll
    for (int i = 0; i < 2; ++i) acc[i] = b1[cog * 2 + i];
    const float* ip = p1 + (size_t)b * 64 * 4096 + p;
    for (int ci = 0; ci < 64; ++ci) {
        float v = ip[(size_t)ci * 4096];
        #pragma unroll
        for (int i = 0; i < 2; ++i) acc[i] += w1[(cog * 2 + i) * 64 + ci] * v;
    }
    float* op = t2 + (size_t)b * 32 * 4096 + p;
    #pragma unroll
    for (int i = 0; i < 2; ++i) op[(size_t)(cog * 2 + i) * 4096] = acc[i];
}

// ---------------- K3: 3x3 conv pad=1, 32->32 on 64x64; grid 1024 (2 oc/thread)
__global__ __launch_bounds__(256) void k_conv3x3_b(const float* __restrict__ t2,
                                                   const float* __restrict__ w2,
                                                   const float* __restrict__ b2,
                                                   float* __restrict__ t3) {
    int blk = blockIdx.x;
    int pt = blk & 15;
    int cog = (blk >> 4) & 15;
    int b = blk >> 8;
    int p = pt * 256 + threadIdx.x;
    int hy = p >> 6, wx = p & 63;
    float acc[2];
    #pragma unroll
    for (int i = 0; i < 2; ++i) acc[i] = b2[cog * 2 + i];
    const float* ip = t2 + (size_t)b * 32 * 4096;
    for (int ci = 0; ci < 32; ++ci) {
        float v[9];
        #pragma unroll
        for (int ky = 0; ky < 3; ++ky) {
            int yy = hy + ky - 1;
            #pragma unroll
            for (int kx = 0; kx < 3; ++kx) {
                int xx = wx + kx - 1;
                bool ok = (yy >= 0 && yy < 64 && xx >= 0 && xx < 64);
                int yc = min(max(yy, 0), 63), xc = min(max(xx, 0), 63);
                float val = ip[(size_t)ci * 4096 + yc * 64 + xc];
                v[ky * 3 + kx] = ok ? val : 0.f;
            }
        }
        #pragma unroll
        for (int i = 0; i < 2; ++i) {
            const float* wp = w2 + (((cog * 2 + i) * 32) + ci) * 9;   // uniform
            float s = acc[i];
            #pragma unroll
            for (int k = 0; k < 9; ++k) s += wp[k] * v[k];
            acc[i] = s;
        }
    }
    float* op = t3 + (size_t)b * 32 * 4096 + p;
    #pragma unroll
    for (int i = 0; i < 2; ++i) op[(size_t)(cog * 2 + i) * 4096] = acc[i];
}

// ---------------- K5: deformable conv, MFMA offsets + MFMA main (v5)
// grid 1024 = strip(256)*4 + b. block 256 = 4 waves.
// Per sub-phase s (16 x-channels): 18 f16-MFMA tiles compute all 2304
// offset values -> soff (half2 py,px); then 2304 gather tasks fill the
// bf16 A-tile; per half h: 9x4 bf16-MFMA accumulate D[64px][64oc].
__global__ __launch_bounds__(256, 3) void k_deform(const float* __restrict__ x,
                                                   const float* __restrict__ t3,
                                                   const __half* __restrict__ w3h,
                                                   const float* __restrict__ b3,
                                                   const unsigned short* __restrict__ wdtb,
                                                   float* __restrict__ out) {
    int blk = blockIdx.x;
    int b = blk & 3;
    int strip = blk >> 2;         // 0..255
    int tid = threadIdx.x;
    int po0 = strip * 16;
    int qy = po0 >> 6;            // strip lies in one quad-row
    int qx0 = po0 & 63;
    int w = tid >> 6;             // wave id
    int lane = tid & 63;
    int lm = lane & 15;
    int lq = lane >> 4;
    int tq = tid & 15;            // pooled-px column this thread serves (fixed)
    int kb = tid >> 4;            // kcol = it*16 + kb

    __shared__ __align__(16) unsigned short alds[64 * 320];   // 40960 B
    __shared__ __align__(16) __half2 soff[2304];              //  9216 B
    __shared__ __align__(16) _Float16 st3t[16 * 40];          //  1280 B

    f32x4 acc[4];
    #pragma unroll
    for (int n = 0; n < 4; ++n) acc[n] = (f32x4){0.f, 0.f, 0.f, 0.f};

    const float* xb = x + (size_t)b * 64 * HX * WX;
    float fybase = (float)(2 * qy);
    float fxbase = (float)(2 * (qx0 + tq));

    // ---- stage t3 tile (32 ci x 16 px) to LDS as fp16, px-major pitch 40
    {
        int px = tid & 15, ci0 = tid >> 4;    // ci0 0..15
        const float* t3p = t3 + (size_t)b * 32 * 4096 + (qy * 64 + qx0 + px);
        st3t[px * 40 + ci0]      = (_Float16)t3p[(size_t)ci0 * 4096];
        st3t[px * 40 + ci0 + 16] = (_Float16)t3p[(size_t)(ci0 + 16) * 4096];
    }
    __syncthreads();
    // B-frag (t3) for the offset MFMA: lane holds t3[px=lm][ci=lq*8+j].
    // Same for every tile/sub-phase -> read once. (byte addr lm*80+lq*16, 16B-aligned)
    const f16x8 bfrag = *(const f16x8*)&st3t[lm * 40 + lq * 8];

    for (int h = 0; h < 2; ++h) {
        #pragma unroll 1
        for (int sl = 0; sl < 2; ++sl) {
            int s = h * 2 + sl;           // sup = 16 channels
            __syncthreads();              // alds+soff free (prev phase done)

            // ---- phase 1a: offsets via f16 MFMA. 18 tiles of 16 off-ch.
            // op1 = w3h rows (lane row lm, k=lq*8+j); D row = t*16+lq*4+r
            // (off-ch), D col = lm (px). chn = s*288 + 2*kcol + eo.
            #pragma unroll
            for (int rep = 0; rep < 5; ++rep) {
                int t = rep * 4 + w;
                if (rep == 4) { if (w >= 2) break; t = 16 + w; }
                const f16x8 afrag = *(const f16x8*)((const _Float16*)w3h
                        + (size_t)(s * 288 + t * 16 + lm) * 32 + lq * 8);
                f32x4 d = __builtin_amdgcn_mfma_f32_16x16x32_f16(
                        afrag, bfrag, (f32x4){0.f, 0.f, 0.f, 0.f}, 0, 0, 0);
                float4 bq = *(const float4*)(b3 + s * 288 + t * 16 + lq * 4);
                int p0 = (t * 8 + lq * 2) * 16 + lm;   // pair-slot kcol*16+px
                soff[p0]      = __floats2half2_rn(d[0] + bq.x, d[1] + bq.y);
                soff[p0 + 16] = __floats2half2_rn(d[2] + bq.z, d[3] + bq.w);
            }
            __syncthreads();              // soff visible

            // ---- phase 1b: prefetch 9 offset pairs (word = it*256 + tid)
            __half2 o2h[9];
            #pragma unroll
            for (int it = 0; it < 9; ++it)
                o2h[it] = soff[it * 256 + tid];
            // bilinear gather -> 4 bf16 A-tile rows per task
            #pragma unroll
            for (int it = 0; it < 9; ++it) {
                int kcol = it * 16 + kb;      // 0..143
                int lc = kcol >= 72;
                int ckk = kcol - 72 * lc;     // 0..71
                int ch = (ckk * 57) >> 9;     // /9
                int kk = ckk - ch * 9;
                int c = s * 16 + lc * 8 + ch;
                int clocal = sl * 144 + kcol; // A column 0..287
                float2 off = __half22float2(o2h[it]);
                float py = off.x + fybase + (float)(kk / 3);
                float px = off.y + fxbase + (float)(kk % 3);
                float y0f = floorf(py), x0f = floorf(px);
                float fy = py - y0f, fx = px - x0f;
                int y0 = (int)y0f, x0 = (int)x0f;
                const float* xp = xb + (size_t)c * (HX * WX);
                float tv[3][3];
                bool fastok = (y0 >= 0) & (y0 <= HX - 3) & (x0 >= 0) & (x0 <= WX - 3);
                if (__all(fastok)) {
                    // whole wave in-bounds: even-aligned float2 pair per row
                    int xe = x0 & ~1;         // even -> 8B-aligned (WX even)
                    int odd = x0 & 1;
                    const float* rp = xp + y0 * WX + xe;
                    #pragma unroll
                    for (int r = 0; r < 3; ++r) {
                        float2 A = *(const float2*)(rp);
                        float2 B = *(const float2*)(rp + 2);
                        tv[r][0] = odd ? A.y : A.x;
                        tv[r][1] = odd ? B.x : A.y;
                        tv[r][2] = odd ? B.y : B.x;
                        rp += WX;
                    }
                } else {
                    #pragma unroll
                    for (int r = 0; r < 3; ++r) {
                        int yy = y0 + r;
                        bool vy = (yy >= 0) & (yy < HX);
                        int yc = min(max(yy, 0), HX - 1);
                        #pragma unroll
                        for (int sx = 0; sx < 3; ++sx) {
                            int xx = x0 + sx;
                            bool vx = (xx >= 0) & (xx < WX);
                            int xc = min(max(xx, 0), WX - 1);
                            float val = xp[yc * WX + xc];
                            tv[r][sx] = (vy & vx) ? val : 0.f;
                        }
                    }
                }
                float h0[3], h1[3];
                #pragma unroll
                for (int r = 0; r < 3; ++r) {
                    h0[r] = tv[r][0] + fx * (tv[r][1] - tv[r][0]);
                    h1[r] = tv[r][1] + fx * (tv[r][2] - tv[r][1]);
                }
                alds[aoff(0 * 16 + tq, clocal)] = f2bf(h0[0] + fy * (h0[1] - h0[0]));
                alds[aoff(1 * 16 + tq, clocal)] = f2bf(h1[0] + fy * (h1[1] - h1[0]));
                alds[aoff(2 * 16 + tq, clocal)] = f2bf(h0[1] + fy * (h0[2] - h0[1]));
                alds[aoff(3 * 16 + tq, clocal)] = f2bf(h1[1] + fy * (h1[2] - h1[1]));
            }
        }
        __syncthreads();          // A-tile (288 cols) visible

        // ---- phase 2: D[64px][64oc] += V[64][288] . W^T  (MFMA bf16)
        int arow = w * 16 + lm;
        const unsigned short* bbase = wdtb + (size_t)(h * 64) * 288;
        #pragma unroll
        for (int ks = 0; ks < 9; ++ks) {
            bf16x8 a = *(const bf16x8*)&alds[aoff(arow, ks * 32 + lq * 8)];
            #pragma unroll
            for (int n = 0; n < 4; ++n) {
                bf16x8 bb = *(const bf16x8*)(bbase + (size_t)(n * 16 + lm) * 288
                                             + ks * 32 + lq * 8);
                acc[n] = __builtin_amdgcn_mfma_f32_16x16x32_bf16(a, bb, acc[n], 0, 0, 0);
            }
        }
    }

    // ---- epilogue via LDS: D lane layout -> [oc][px] -> coalesced stores
    __syncthreads();              // all phase-2 reads of alds complete
    float* dlds = (float*)alds;   // 64*65 = 4160 floats (16.6 KB of 40.9)
    #pragma unroll
    for (int n = 0; n < 4; ++n) {
        int oc = n * 16 + lm;
        #pragma unroll
        for (int r = 0; r < 4; ++r) {
            int px = w * 16 + lq * 4 + r;     // = sub*16 + q
            dlds[oc * 65 + px] = acc[n][r];
        }
    }
    __syncthreads();
    {
        int oc = tid >> 2;
        int sy = (tid >> 1) & 1;
        int qh = (tid & 1) * 8;
        float* orow = out + (((size_t)b * 64 + oc) * 128 + 2 * qy + sy) * 128 + 2 * qx0;
        const float* d0 = &dlds[oc * 65 + (sy * 2 + 0) * 16];
        const float* d1 = &dlds[oc * 65 + (sy * 2 + 1) * 16];
        #pragma unroll
        for (int i = 0; i < 8; ++i) {
            int q = qh + i;
            *(float2*)(orow + 2 * q) = make_float2(d0[q], d1[q]);
        }
    }
}

extern "C" void kernel_launch(void* const* d_in, const int* in_sizes, int n_in,
                              void* d_out, int out_size, void* d_ws, size_t ws_size,
                              hipStream_t stream) {
    const float* x  = (const float*)d_in[0];
    const float* w0 = (const float*)d_in[1];
    const float* b0 = (const float*)d_in[2];
    const float* w1 = (const float*)d_in[3];
    const float* b1 = (const float*)d_in[4];
    const float* w2 = (const float*)d_in[5];
    const float* b2 = (const float*)d_in[6];
    const float* w3 = (const float*)d_in[7];
    const float* b3 = (const float*)d_in[8];
    const float* wd = (const float*)d_in[9];
    float* out = (float*)d_out;

    float* ws = (float*)d_ws;
    float* p1    = ws;                       // 1,048,576 floats
    float* t2    = p1 + 1048576;             //   524,288
    float* t3    = t2 + 524288;              //   524,288
    unsigned short* wdtb = (unsigned short*)(t3 + 524288);  // 36,864 bf16
    __half* w3h = (__half*)(wdtb + 36864);   // 36,864 fp16 (16B-aligned)

    k_wdt<<<288, 256, 0, stream>>>(wd, w3, wdtb, w3h);
    k_conv0_pool<<<1024, 256, 0, stream>>>(x, w0, b0, p1);
    k_conv1x1_a<<<1024, 256, 0, stream>>>(p1, w1, b1, t2);
    k_conv3x3_b<<<1024, 256, 0, stream>>>(t2, w2, b2, t3);
    k_deform<<<1024, 256, 0, stream>>>(x, t3, w3h, b3, wdtb, out);
}